// Round 1
// baseline (831.243 us; speedup 1.0000x reference)
//
#include <hip/hip_runtime.h>
#include <math.h>

// Problem dims (from setup_inputs): x[4,2048,4096] A[8,16,4096] B[8,4096,16]
// Wr[8,4096] br[8] -> out[4,2048,4096], all fp32.
#define M_TOK 8192
#define D_DIM 4096
#define H_N   8
#define R_N   16
#define O_DIM 4096
// GEMM1 virtual weight matrix: rows 0..127 = A flat [128][4096],
// rows 128..135 = Wr [8][4096], rows 136..143 = zero pad. N1 = 144.

// ---------------- kernel 0: transpose B [H,O,R] -> BtT [O][H*R] ----------------
// BtT[o*128 + k] = B[h*O*R + o*R + r], k = h*16+r. 524288 elements.
__global__ __launch_bounds__(256) void k0_transposeB(const float* __restrict__ B,
                                                     float* __restrict__ BtT) {
    int e = blockIdx.x * 256 + threadIdx.x;   // e = o*128 + k
    int o = e >> 7;
    int k = e & 127;
    int h = k >> 4;
    int r = k & 15;
    BtT[e] = B[(size_t)h * (O_DIM * R_N) + (size_t)o * R_N + r];
}

// ---------------- kernel 1: GEMM1 (low + logits) ----------------
// C[n][j] = sum_d X[n][d] * W144[j][d];  j<128 -> low, 128<=j<136 -> logits.
// Tile: 64 tokens x 48 cols, Kc=32. grid = (8192/64)*3 = 384 blocks.
__global__ __launch_bounds__(256) void k1_gemm1(const float* __restrict__ X,
                                                const float* __restrict__ A,
                                                const float* __restrict__ Wr,
                                                float* __restrict__ low,
                                                float* __restrict__ logits) {
    __shared__ float Xs[64][36];   // +4 pad keeps float4 alignment, breaks pow2 stride
    __shared__ float Ws[48][36];
    const int bx   = blockIdx.x;
    const int mblk = bx / 3;
    const int nblk = bx - mblk * 3;
    const int m0 = mblk * 64;
    const int n0 = nblk * 48;
    const int tid = threadIdx.x;
    const int tx = tid & 15;       // col group
    const int ty = tid >> 4;       // row group

    float acc[4][3] = {};

    for (int k0 = 0; k0 < D_DIM; k0 += 32) {
        // stage X tile: 64 rows x 32 cols = 512 float4
        #pragma unroll
        for (int i = 0; i < 2; ++i) {
            int idx = tid + i * 256;          // 0..511
            int row = idx >> 3;
            int c4  = idx & 7;
            float4 v = *(const float4*)(X + (size_t)(m0 + row) * D_DIM + k0 + c4 * 4);
            *(float4*)&Xs[row][c4 * 4] = v;
        }
        // stage W tile: 48 rows x 32 cols = 384 float4
        #pragma unroll
        for (int i = 0; i < 2; ++i) {
            int idx = tid + i * 256;
            if (idx < 384) {
                int row = idx >> 3;
                int c4  = idx & 7;
                int j   = n0 + row;
                float4 v;
                if (j < 128)       v = *(const float4*)(A  + (size_t)j * D_DIM + k0 + c4 * 4);
                else if (j < 136)  v = *(const float4*)(Wr + (size_t)(j - 128) * D_DIM + k0 + c4 * 4);
                else               v = make_float4(0.f, 0.f, 0.f, 0.f);
                *(float4*)&Ws[row][c4 * 4] = v;
            }
        }
        __syncthreads();
        #pragma unroll
        for (int kk = 0; kk < 32; kk += 4) {
            float4 xv[4], wv[3];
            #pragma unroll
            for (int i = 0; i < 4; ++i) xv[i] = *(const float4*)&Xs[ty + 16 * i][kk];
            #pragma unroll
            for (int j = 0; j < 3; ++j) wv[j] = *(const float4*)&Ws[tx + 16 * j][kk];
            #pragma unroll
            for (int i = 0; i < 4; ++i)
                #pragma unroll
                for (int j = 0; j < 3; ++j)
                    acc[i][j] += xv[i].x * wv[j].x + xv[i].y * wv[j].y +
                                 xv[i].z * wv[j].z + xv[i].w * wv[j].w;
        }
        __syncthreads();
    }

    #pragma unroll
    for (int i = 0; i < 4; ++i) {
        int row = m0 + ty + 16 * i;
        #pragma unroll
        for (int j = 0; j < 3; ++j) {
            int col = n0 + tx + 16 * j;
            if (col < 128)      low[(size_t)row * 128 + col] = acc[i][j];
            else if (col < 136) logits[(size_t)row * 8 + (col - 128)] = acc[i][j];
        }
    }
}

// ---------------- kernel 1.5: softmax + scale (in place on low -> W2) ----------------
// W2[n][h*16+r] = low[n][h*16+r] * 16 * softmax_h(logits[n]+br)   (H*SCALING = 16)
__global__ __launch_bounds__(256) void k15_softmax_scale(float* __restrict__ low,
                                                         const float* __restrict__ logits,
                                                         const float* __restrict__ br) {
    __shared__ float ss[64][8];
    const int t0  = blockIdx.x * 64;
    const int tid = threadIdx.x;
    if (tid < 64) {
        int tok = t0 + tid;
        float l[8];
        float m = -1e30f;
        #pragma unroll
        for (int h = 0; h < 8; ++h) {
            l[h] = logits[(size_t)tok * 8 + h] + br[h];
            m = fmaxf(m, l[h]);
        }
        float s = 0.f;
        #pragma unroll
        for (int h = 0; h < 8; ++h) { l[h] = __expf(l[h] - m); s += l[h]; }
        float inv = 16.0f / s;
        #pragma unroll
        for (int h = 0; h < 8; ++h) ss[tid][h] = l[h] * inv;
    }
    __syncthreads();
    #pragma unroll
    for (int i = 0; i < 32; ++i) {
        int e   = tid + i * 256;          // 0..8191
        int tok = e >> 7;
        int j   = e & 127;
        low[(size_t)(t0 + tok) * 128 + j] *= ss[tok][j >> 4];
    }
}

// ---------------- kernel 2: GEMM2 ----------------
// out[n][o] = sum_k W2[n][k] * BtT[o][k].  Tile 64 tokens x 128 outs, Kc=32.
// grid = 128 mblks * 32 nblks = 4096 blocks.
__global__ __launch_bounds__(256) void k2_gemm2(const float* __restrict__ W2,
                                                const float* __restrict__ BtT,
                                                float* __restrict__ out) {
    __shared__ float W2s[64][36];
    __shared__ float Bs[128][36];
    const int nblk = blockIdx.x & 31;
    const int mblk = blockIdx.x >> 5;
    const int m0 = mblk * 64;
    const int n0 = nblk * 128;
    const int tid = threadIdx.x;
    const int tx = tid & 15;
    const int ty = tid >> 4;

    float acc[4][8] = {};

    for (int k0 = 0; k0 < 128; k0 += 32) {
        #pragma unroll
        for (int i = 0; i < 2; ++i) {
            int idx = tid + i * 256;      // 0..511  (64x32 / 4)
            int row = idx >> 3;
            int c4  = idx & 7;
            *(float4*)&W2s[row][c4 * 4] =
                *(const float4*)(W2 + (size_t)(m0 + row) * 128 + k0 + c4 * 4);
        }
        #pragma unroll
        for (int i = 0; i < 4; ++i) {
            int idx = tid + i * 256;      // 0..1023 (128x32 / 4)
            int row = idx >> 3;
            int c4  = idx & 7;
            *(float4*)&Bs[row][c4 * 4] =
                *(const float4*)(BtT + (size_t)(n0 + row) * 128 + k0 + c4 * 4);
        }
        __syncthreads();
        #pragma unroll
        for (int kk = 0; kk < 32; kk += 4) {
            float4 xv[4], wv[8];
            #pragma unroll
            for (int i = 0; i < 4; ++i) xv[i] = *(const float4*)&W2s[ty + 16 * i][kk];
            #pragma unroll
            for (int j = 0; j < 8; ++j) wv[j] = *(const float4*)&Bs[tx + 16 * j][kk];
            #pragma unroll
            for (int i = 0; i < 4; ++i)
                #pragma unroll
                for (int j = 0; j < 8; ++j)
                    acc[i][j] += xv[i].x * wv[j].x + xv[i].y * wv[j].y +
                                 xv[i].z * wv[j].z + xv[i].w * wv[j].w;
        }
        __syncthreads();
    }

    #pragma unroll
    for (int i = 0; i < 4; ++i) {
        size_t row = m0 + ty + 16 * i;
        #pragma unroll
        for (int j = 0; j < 8; ++j)
            out[row * O_DIM + n0 + tx + 16 * j] = acc[i][j];
    }
}

extern "C" void kernel_launch(void* const* d_in, const int* in_sizes, int n_in,
                              void* d_out, int out_size, void* d_ws, size_t ws_size,
                              hipStream_t stream) {
    const float* x  = (const float*)d_in[0];
    const float* A  = (const float*)d_in[1];
    const float* B  = (const float*)d_in[2];
    const float* Wr = (const float*)d_in[3];
    const float* br = (const float*)d_in[4];
    float* out = (float*)d_out;

    // workspace layout (floats): BtT [4096*128] | low/W2 [8192*128] | logits [8192*8]
    float* ws     = (float*)d_ws;
    float* BtT    = ws;                      // 524288 floats (2 MB)
    float* low    = BtT + 524288;            // 1048576 floats (4 MB), reused as W2
    float* logits = low + 1048576;           // 65536 floats (0.25 MB)

    k0_transposeB<<<dim3(2048), dim3(256), 0, stream>>>(B, BtT);
    k1_gemm1<<<dim3(384), dim3(256), 0, stream>>>(x, A, Wr, low, logits);
    k15_softmax_scale<<<dim3(128), dim3(256), 0, stream>>>(low, logits, br);
    k2_gemm2<<<dim3(4096), dim3(256), 0, stream>>>(low, BtT, out);
}

// Round 2
// 295.204 us; speedup vs baseline: 2.8158x; 2.8158x over previous
//
#include <hip/hip_runtime.h>
#include <math.h>

// Dims: x[8192,4096] A[128,4096] B[8,4096,16] Wr[8,4096] br[8] -> out[8192,4096]
#define D_DIM 4096
#define O_DIM 4096
// GEMM1 virtual weight: rows 0..127 = A, 128..135 = Wr, 136..143 = zero. N1=144.
#define KSPLIT 4

typedef __attribute__((ext_vector_type(8))) short short8;
typedef __attribute__((ext_vector_type(4))) float floatx4;

__device__ inline unsigned short f2bf(float f) {
    union { float f; unsigned u; } v; v.f = f;
    unsigned r = v.u + 0x7FFF + ((v.u >> 16) & 1);   // RNE
    return (unsigned short)(r >> 16);
}

// ---------- prep A: W1bf [144][4096] bf16 from A(128 rows) + Wr(8) + zeros(8) ----------
__global__ __launch_bounds__(256) void k0a_prepW1(const float* __restrict__ A,
                                                  const float* __restrict__ Wr,
                                                  unsigned short* __restrict__ W1bf) {
    int e = (blockIdx.x * 256 + threadIdx.x) * 4;    // 144*4096 = 589824 elems
    int row = e >> 12;
    int col = e & 4095;
    float4 v;
    if (row < 128)      v = *(const float4*)(A + (size_t)row * D_DIM + col);
    else if (row < 136) v = *(const float4*)(Wr + (size_t)(row - 128) * D_DIM + col);
    else                v = make_float4(0.f, 0.f, 0.f, 0.f);
    ushort4 o; o.x = f2bf(v.x); o.y = f2bf(v.y); o.z = f2bf(v.z); o.w = f2bf(v.w);
    *(ushort4*)(W1bf + e) = o;
}

// ---------- prep B: Btbf [4096][128] bf16, Btbf[o][h*16+r] = B[h][o][r] ----------
__global__ __launch_bounds__(256) void k0b_prepBt(const float* __restrict__ B,
                                                  unsigned short* __restrict__ Btbf) {
    int e = (blockIdx.x * 256 + threadIdx.x) * 4;    // 4096*128 = 524288 elems
    int o = e >> 7;
    int k = e & 127;          // k%4==0, so all 4 elems share h
    int h = k >> 4;
    int r = k & 15;
    float4 v = *(const float4*)(B + (size_t)h * (O_DIM * 16) + (size_t)o * 16 + r);
    ushort4 w; w.x = f2bf(v.x); w.y = f2bf(v.y); w.z = f2bf(v.z); w.w = f2bf(v.w);
    *(ushort4*)(Btbf + e) = w;
}

// ---------- GEMM1: P[kslice][8192][144] = x * W1^T (per K-slice), bf16 MFMA ----------
// grid = 64 mblks * KSPLIT; block = 256 (4 waves). Mtile=128 (wave: 2 Msub x 9 N).
__global__ __launch_bounds__(256) void k1_gemm1(const float* __restrict__ X,
                                                const unsigned short* __restrict__ W1bf,
                                                float* __restrict__ P) {
    __shared__ short Xs[128][72];    // 64 bf16 + 8 pad -> b128 reads spread 8 bank-groups
    __shared__ short Ws[144][72];
    const int kslice = blockIdx.x & (KSPLIT - 1);
    const int mblk   = blockIdx.x >> 2;
    const int m0     = mblk * 128;
    const int kbase  = kslice * (D_DIM / KSPLIT);    // 1024
    const int tid  = threadIdx.x;
    const int wave = tid >> 6;
    const int lane = tid & 63;
    const int lrow = lane & 15;
    const int quad = lane >> 4;

    floatx4 acc[2][9];
    #pragma unroll
    for (int i = 0; i < 2; ++i)
        #pragma unroll
        for (int n = 0; n < 9; ++n) acc[i][n] = (floatx4)(0.f);

    for (int it = 0; it < (D_DIM / KSPLIT) / 64; ++it) {   // 16 chunks of BK=64
        const int k0c = kbase + it * 64;
        // stage X: 128x64 fp32 -> bf16.  2048 float4 / 256 thr = 8 each
        #pragma unroll
        for (int i = 0; i < 8; ++i) {
            int e   = tid + i * 256;        // 0..2047
            int row = e >> 4;               // 16 float4 per row
            int c4  = e & 15;
            float4 v = *(const float4*)(X + (size_t)(m0 + row) * D_DIM + k0c + c4 * 4);
            ushort4 o; o.x = f2bf(v.x); o.y = f2bf(v.y); o.z = f2bf(v.z); o.w = f2bf(v.w);
            *(ushort4*)&Xs[row][c4 * 4] = o;
        }
        // stage W: 144x64 bf16.  1152 x 16B / 256 thr = 4.5
        #pragma unroll
        for (int i = 0; i < 5; ++i) {
            int e = tid + i * 256;
            if (e < 1152) {
                int row = e >> 3;           // 8 x16B per row
                int c8  = e & 7;
                uint4 v = *(const uint4*)(W1bf + (size_t)row * D_DIM + k0c + c8 * 8);
                *(uint4*)&Ws[row][c8 * 8] = v;
            }
        }
        __syncthreads();
        #pragma unroll
        for (int ks = 0; ks < 2; ++ks) {    // 2 MFMA k-steps of 32
            const int koff = ks * 32 + quad * 8;
            short8 a[2];
            #pragma unroll
            for (int i = 0; i < 2; ++i)
                a[i] = *(const short8*)&Xs[wave * 32 + i * 16 + lrow][koff];
            #pragma unroll
            for (int n = 0; n < 9; ++n) {
                short8 b = *(const short8*)&Ws[n * 16 + lrow][koff];
                #pragma unroll
                for (int i = 0; i < 2; ++i)
                    acc[i][n] = __builtin_amdgcn_mfma_f32_16x16x32_bf16(a[i], b, acc[i][n], 0, 0, 0);
            }
        }
        __syncthreads();
    }

    float* Pk = P + (size_t)kslice * (8192 * 144);
    #pragma unroll
    for (int i = 0; i < 2; ++i) {
        #pragma unroll
        for (int n = 0; n < 9; ++n) {
            #pragma unroll
            for (int reg = 0; reg < 4; ++reg) {
                int row = m0 + wave * 32 + i * 16 + quad * 4 + reg;   // C/D: row=(lane>>4)*4+reg
                int col = n * 16 + lrow;                              //      col=lane&15
                Pk[(size_t)row * 144 + col] = acc[i][n][reg];
            }
        }
    }
}

// ---------- reduce split-K + softmax + scale -> W2 bf16 [8192][128] ----------
__global__ __launch_bounds__(256) void k15_reduce_softmax(const float* __restrict__ P,
                                                          const float* __restrict__ br,
                                                          unsigned short* __restrict__ W2) {
    __shared__ float S[64][148];
    const int t0  = blockIdx.x * 64;
    const int tid = threadIdx.x;
    // sum 4 partials: 64x144 = 2304 float4 per partial / 256 thr = 9 each
    #pragma unroll
    for (int i = 0; i < 9; ++i) {
        int e   = tid + i * 256;
        int row = e / 36;                 // 36 float4 per row
        int c4  = e - row * 36;
        size_t off = (size_t)(t0 + row) * 144 + c4 * 4;
        float4 s = *(const float4*)(P + off);
        #pragma unroll
        for (int p = 1; p < KSPLIT; ++p) {
            float4 v = *(const float4*)(P + (size_t)p * (8192 * 144) + off);
            s.x += v.x; s.y += v.y; s.z += v.z; s.w += v.w;
        }
        *(float4*)&S[row][c4 * 4] = s;
    }
    __syncthreads();
    if (tid < 64) {
        float l[8]; float m = -1e30f;
        #pragma unroll
        for (int h = 0; h < 8; ++h) { l[h] = S[tid][128 + h] + br[h]; m = fmaxf(m, l[h]); }
        float s = 0.f;
        #pragma unroll
        for (int h = 0; h < 8; ++h) { l[h] = __expf(l[h] - m); s += l[h]; }
        float inv = 16.0f / s;            // H * SCALING = 16
        #pragma unroll
        for (int h = 0; h < 8; ++h) S[tid][136 + h] = l[h] * inv;   // cols 136..143 were pad
    }
    __syncthreads();
    // write W2 bf16: 64x128 / 4 per thread
    #pragma unroll
    for (int i = 0; i < 8; ++i) {
        int e   = tid + i * 256;          // 0..2047 (4-elem units)
        int tok = e >> 5;                 // 32 units per row
        int c4  = e & 31;
        int col = c4 * 4;
        float sc = S[tok][136 + (col >> 4)];
        ushort4 o;
        o.x = f2bf(S[tok][col + 0] * sc);
        o.y = f2bf(S[tok][col + 1] * sc);
        o.z = f2bf(S[tok][col + 2] * sc);
        o.w = f2bf(S[tok][col + 3] * sc);
        *(ushort4*)(W2 + (size_t)(t0 + tok) * 128 + col) = o;
    }
}

// ---------- GEMM2: out[8192][4096] = W2[8192][128] * Btbf[4096][128]^T ----------
// grid = 64 mblks x 32 nblks; tile 128x128, K=128 fully staged.
__global__ __launch_bounds__(256) void k2_gemm2(const unsigned short* __restrict__ W2,
                                                const unsigned short* __restrict__ Btbf,
                                                float* __restrict__ out) {
    __shared__ short Ms[128][136];   // 128 bf16 + 8 pad
    __shared__ short Bs[128][136];
    const int nblk = blockIdx.x & 31;
    const int mblk = blockIdx.x >> 5;
    const int m0 = mblk * 128, n0 = nblk * 128;
    const int tid  = threadIdx.x;
    const int wave = tid >> 6;
    const int lane = tid & 63;
    const int lrow = lane & 15;
    const int quad = lane >> 4;

    // stage both tiles: 2048 x16B each / 256 thr = 8 each
    #pragma unroll
    for (int i = 0; i < 8; ++i) {
        int e   = tid + i * 256;
        int row = e >> 4;                 // 16 x16B per row
        int c8  = e & 15;
        *(uint4*)&Ms[row][c8 * 8] = *(const uint4*)(W2   + (size_t)(m0 + row) * 128 + c8 * 8);
        *(uint4*)&Bs[row][c8 * 8] = *(const uint4*)(Btbf + (size_t)(n0 + row) * 128 + c8 * 8);
    }
    __syncthreads();

    floatx4 acc[2][8];
    #pragma unroll
    for (int i = 0; i < 2; ++i)
        #pragma unroll
        for (int n = 0; n < 8; ++n) acc[i][n] = (floatx4)(0.f);

    #pragma unroll
    for (int ks = 0; ks < 4; ++ks) {
        const int koff = ks * 32 + quad * 8;
        short8 a[2];
        #pragma unroll
        for (int i = 0; i < 2; ++i)
            a[i] = *(const short8*)&Ms[wave * 32 + i * 16 + lrow][koff];
        #pragma unroll
        for (int n = 0; n < 8; ++n) {
            short8 b = *(const short8*)&Bs[n * 16 + lrow][koff];
            #pragma unroll
            for (int i = 0; i < 2; ++i)
                acc[i][n] = __builtin_amdgcn_mfma_f32_16x16x32_bf16(a[i], b, acc[i][n], 0, 0, 0);
        }
    }

    #pragma unroll
    for (int i = 0; i < 2; ++i) {
        #pragma unroll
        for (int n = 0; n < 8; ++n) {
            #pragma unroll
            for (int reg = 0; reg < 4; ++reg) {
                int row = m0 + wave * 32 + i * 16 + quad * 4 + reg;
                int col = n0 + n * 16 + lrow;
                out[(size_t)row * O_DIM + col] = acc[i][n][reg];
            }
        }
    }
}

extern "C" void kernel_launch(void* const* d_in, const int* in_sizes, int n_in,
                              void* d_out, int out_size, void* d_ws, size_t ws_size,
                              hipStream_t stream) {
    const float* x  = (const float*)d_in[0];
    const float* A  = (const float*)d_in[1];
    const float* B  = (const float*)d_in[2];
    const float* Wr = (const float*)d_in[3];
    const float* br = (const float*)d_in[4];
    float* out = (float*)d_out;

    // ws layout (float units):
    // P:    KSPLIT * 8192 * 144          = 4,718,592 floats
    // W2:   8192*128 bf16                =   524,288 float-slots
    // W1bf: 144*4096 bf16                =   294,912 float-slots
    // Btbf: 4096*128 bf16                =   262,144 float-slots    total ~23.2 MB
    float* ws = (float*)d_ws;
    float*          P     = ws;
    unsigned short* W2    = (unsigned short*)(ws + 4718592);
    unsigned short* W1bf  = (unsigned short*)(ws + 4718592 + 524288);
    unsigned short* Btbf  = (unsigned short*)(ws + 4718592 + 524288 + 294912);

    k0a_prepW1<<<dim3(576), dim3(256), 0, stream>>>(A, Wr, W1bf);
    k0b_prepBt<<<dim3(512), dim3(256), 0, stream>>>(B, Btbf);
    k1_gemm1<<<dim3(64 * KSPLIT), dim3(256), 0, stream>>>(x, W1bf, P);
    k15_reduce_softmax<<<dim3(128), dim3(256), 0, stream>>>(P, br, W2);
    k2_gemm2<<<dim3(64 * 32), dim3(256), 0, stream>>>(W2, Btbf, out);
}